// Round 16
// baseline (106.643 us; speedup 1.0000x reference)
//
#include <hip/hip_runtime.h>

// mads (type='nwd', kernel='gauss') forward: Gaussian-kernel attention.
// out[b,q,v] = sum_k softmax_k(-0.5*||K[b,k]*W - Q[b,q]*W||^2) * V[b,k,v]
//
// R16: m97-style LDS staging. prep packs K(hi/lo) + V^T into lane-major
// 16B/lane tiles; main loop double-buffers each wave's next 32-key tile in
// wave-private LDS via 6x global_load_lds(width16) issued one round ahead,
// counted s_waitcnt vmcnt(6) (never 0 mid-loop), ds_read -> R9's proven
// compute body. Global latency leaves the per-round chain entirely; no
// VGPR growth (the spill wall R7/R10/R11/R12 hit is bypassed via LDS);
// wave-private buffers -> no barriers in the main loop.

#define L2E 1.4426950408889634f

typedef float f32x4 __attribute__((ext_vector_type(4)));
typedef short s16x8 __attribute__((ext_vector_type(8)));

__device__ __forceinline__ unsigned int f2bf(float f) {
    unsigned int u = __float_as_uint(f);
    return (u + 0x7FFFu + ((u >> 16) & 1u)) >> 16;   // RNE f32->bf16
}
__device__ __forceinline__ float bf2f(unsigned int h) {
    return __uint_as_float(h << 16);
}
__device__ __forceinline__ float exp2_hw(float x) {
    float r;
    asm("v_exp_f32 %0, %1" : "=v"(r) : "v"(x));      // r = 2^x
    return r;
}
__device__ __forceinline__ unsigned int cvt_pk_bf16(float lo, float hi) {
    unsigned int r;
    asm("v_cvt_pk_bf16_f32 %0, %1, %2" : "=v"(r) : "v"(lo), "v"(hi));
    return r;
}

// ---------------- pre-pass: K2S only (-0.5*|k*w|^2) ----------------
__global__ __launch_bounds__(256)
void prep_k2_kernel(const float* __restrict__ K, const float* __restrict__ Wp,
                    float* __restrict__ K2S)
{
    const size_t gtid = (size_t)blockIdx.x * 256 + threadIdx.x;
    const int row = (int)(gtid >> 3);
    const int c0  = ((int)gtid & 7) * 4;
    const float4 k = *(const float4*)(K + (size_t)row * 32 + c0);
    const float4 w = *(const float4*)(Wp + c0);
    float ks0 = k.x * w.x, ks1 = k.y * w.y, ks2 = k.z * w.z, ks3 = k.w * w.w;
    float pk = ks0 * ks0 + ks1 * ks1 + ks2 * ks2 + ks3 * ks3;
    pk += __shfl_xor(pk, 1);
    pk += __shfl_xor(pk, 2);
    pk += __shfl_xor(pk, 4);
    if (c0 == 0) K2S[row] = -0.5f * pk;
}

// ---------------- pre-pass: pack 6 staged streams, lane-major ----------------
// PKS[b][t][i][lane][8] bf16, t = 32-key tile 0..127, i stream:
//  0: khi keys t*32+qi      dims g*8..+7     (lane = g*16+qi)
//  1: khi keys t*32+16+qi   dims g*8..+7
//  2: klo keys t*32+qi      3: klo keys t*32+16+qi
//  4: V^T  v=qi    keys t*32+g*8..+7
//  5: V^T  v=16+qi keys t*32+g*8..+7
__global__ __launch_bounds__(256)
void prep_pack_kernel(const float* __restrict__ K, const float* __restrict__ V,
                      const float* __restrict__ Wp, unsigned short* __restrict__ PKS)
{
    const size_t gtid = (size_t)blockIdx.x * 256 + threadIdx.x;  // < 393216
    const int lane = (int)(gtid & 63);
    const int tmp  = (int)(gtid >> 6);
    const int i    = tmp % 6;
    const int tmp2 = tmp / 6;
    const int t    = tmp2 & 127;
    const int b    = tmp2 >> 7;
    const int qi   = lane & 15;
    const int g    = lane >> 4;

    s16x8 o;
    if (i < 4) {
        const int key = t * 32 + ((i & 1) ? 16 : 0) + qi;
        const int d0  = g * 8;
        const float* kp = K + ((size_t)(b * 4096 + key)) * 32 + d0;
        const float* wp = Wp + d0;
        #pragma unroll
        for (int j = 0; j < 8; ++j) {
            float ks = kp[j] * wp[j];
            unsigned int h = f2bf(ks);
            o[j] = (i < 2) ? (short)h : (short)f2bf(ks - bf2f(h));
        }
    } else {
        const int v  = ((i == 5) ? 16 : 0) + qi;
        const int k0 = t * 32 + g * 8;
        const float* vp = V + ((size_t)(b * 4096 + k0)) * 32 + v;
        #pragma unroll
        for (int j = 0; j < 8; ++j) o[j] = (short)f2bf(vp[(size_t)j * 32]);
    }
    *(s16x8*)(PKS + gtid * 8) = o;
}

// ---------------- main kernel: 512 threads = 8 waves, LDS-staged ----------------
__global__ __launch_bounds__(512, 2)
void mads_main_kernel(const unsigned short* __restrict__ PKS,
                      const float* __restrict__ K2S,
                      const float* __restrict__ Q,
                      const float* __restrict__ Wp,
                      float* __restrict__ OUT)
{
    constexpr int N = 4096, D = 32;
    constexpr int NW = 8;          // waves per WG
    constexpr int TPW = 16;        // 32-key tiles per wave (512 keys)

    __shared__ __align__(16) unsigned short stg[NW][2][6][512];  // 96 KB
    __shared__ __align__(16) unsigned int pbuf[NW][4][16][16];   // 32 KB
    __shared__ float lbuf[NW][4][16];
    __shared__ float sumb[4][32][16];

    const int tid  = threadIdx.x;
    const int lane = tid & 63;
    const int w    = tid >> 6;
    const int g    = lane >> 4;
    const int qi   = lane & 15;
    // XCD-locality swizzle: bid%8 -> XCD; batch b owns XCD b.
    const int b    = blockIdx.x & 7;
    const int q0   = (blockIdx.x >> 3) * 64;

    for (int i = tid; i < 4 * 32 * 16; i += 512) ((float*)sumb)[i] = 0.f;

    // Q fragments (B-operand), hi/lo split + per-query shift -0.5*q2*L2E
    float w8[8];
    {
        const float* wp = Wp + g * 8;
        #pragma unroll
        for (int j = 0; j < 8; ++j) w8[j] = wp[j];
    }
    s16x8 qhi[4], qlo[4];
    float nq2L[4];
    #pragma unroll
    for (int sub = 0; sub < 4; ++sub) {
        const float* qp = Q + ((size_t)(b * N + q0 + sub * 16 + qi)) * D + g * 8;
        float s = 0.f;
        #pragma unroll
        for (int j = 0; j < 8; ++j) {
            float qs = qp[j] * w8[j];
            s = fmaf(qs, qs, s);
            unsigned int h = f2bf(qs);
            qhi[sub][j] = (short)h;
            qlo[sub][j] = (short)f2bf(qs - bf2f(h));
        }
        s += __shfl_xor(s, 16);
        s += __shfl_xor(s, 32);
        nq2L[sub] = -0.5f * s * L2E;
    }

    f32x4 acc[4][2];
    #pragma unroll
    for (int s = 0; s < 4; ++s)
        #pragma unroll
        for (int v = 0; v < 2; ++v)
            #pragma unroll
            for (int i = 0; i < 4; ++i) acc[s][v][i] = 0.f;

    float l_run[4] = {0.f, 0.f, 0.f, 0.f};
    const int pcr = (g + (qi >> 1)) & 3;
    const int tbase = w * TPW;

    // per-lane packed-global base for this wave's tiles
    const unsigned short* pks_base = PKS + ((size_t)(b * 128 + tbase) * 6) * 512 + lane * 8;

    // stage tile (tbase+t) into stg[w][buf]: 6 x global_load_lds width-16,
    // wave-uniform LDS base + lane*16 (linear layout by construction).
    auto stage = [&](int buf, int t) {
        const unsigned short* gp = pks_base + (size_t)t * 6 * 512;
        #pragma unroll
        for (int i = 0; i < 6; ++i)
            __builtin_amdgcn_global_load_lds((const void*)(gp + i * 512),
                                             (void*)&stg[w][buf][i][0], 16, 0, 0);
    };

    stage(0, 0);   // prologue: first tile in flight

    for (int rnd = 0; rnd < TPW; ++rnd) {
        const int cur = rnd & 1;
        const int kb  = (tbase + rnd) * 32;

        // k2 direct loads issued BEFORE next stage (FIFO: covered by vmcnt(6))
        const f32x4 k2c0 = *(const f32x4*)(K2S + b * N + kb + g * 4);
        const f32x4 k2c1 = *(const f32x4*)(K2S + b * N + kb + 16 + g * 4);

        if (rnd < TPW - 1) {
            stage(cur ^ 1, rnd + 1);                       // 6 loads in flight
            asm volatile("s_waitcnt vmcnt(6)" ::: "memory");  // current tile + k2 done
        } else {
            asm volatile("s_waitcnt vmcnt(0)" ::: "memory");
        }

        const s16x8 kh0 = *(const s16x8*)&stg[w][cur][0][lane * 8];
        const s16x8 kh1 = *(const s16x8*)&stg[w][cur][1][lane * 8];
        const s16x8 kl0 = *(const s16x8*)&stg[w][cur][2][lane * 8];
        const s16x8 kl1 = *(const s16x8*)&stg[w][cur][3][lane * 8];
        const s16x8 vf0 = *(const s16x8*)&stg[w][cur][4][lane * 8];
        const s16x8 vf1 = *(const s16x8*)&stg[w][cur][5][lane * 8];

        // ---- QK^T (split precision) + exp + P write (R9 body) ----
        #pragma unroll
        for (int sub = 0; sub < 4; ++sub) {
            f32x4 sv[2];
            sv[0] = k2c0;
            sv[1] = k2c1;
            sv[0] = __builtin_amdgcn_mfma_f32_16x16x32_bf16(kl0, qhi[sub], sv[0], 0, 0, 0);
            sv[0] = __builtin_amdgcn_mfma_f32_16x16x32_bf16(kh0, qlo[sub], sv[0], 0, 0, 0);
            sv[0] = __builtin_amdgcn_mfma_f32_16x16x32_bf16(kh0, qhi[sub], sv[0], 0, 0, 0);
            sv[1] = __builtin_amdgcn_mfma_f32_16x16x32_bf16(kl1, qhi[sub], sv[1], 0, 0, 0);
            sv[1] = __builtin_amdgcn_mfma_f32_16x16x32_bf16(kh1, qlo[sub], sv[1], 0, 0, 0);
            sv[1] = __builtin_amdgcn_mfma_f32_16x16x32_bf16(kh1, qhi[sub], sv[1], 0, 0, 0);

            float p[8];
            #pragma unroll
            for (int kst = 0; kst < 2; ++kst)
                #pragma unroll
                for (int r = 0; r < 4; ++r)
                    p[kst * 4 + r] = exp2_hw(fmaf(sv[kst][r], L2E, nq2L[sub]));

            l_run[sub] += ((p[0] + p[1]) + (p[2] + p[3]))
                        + ((p[4] + p[5]) + (p[6] + p[7]));

            unsigned int pd[2][2];
            pd[0][0] = cvt_pk_bf16(p[0], p[1]);
            pd[0][1] = cvt_pk_bf16(p[2], p[3]);
            pd[1][0] = cvt_pk_bf16(p[4], p[5]);
            pd[1][1] = cvt_pk_bf16(p[6], p[7]);
            #pragma unroll
            for (int kst = 0; kst < 2; ++kst) {
                int c  = kst * 2 + (g >> 1);
                int pc = (c + (qi >> 1)) & 3;
                unsigned long long pack64 =
                    (unsigned long long)pd[kst][0] |
                    ((unsigned long long)pd[kst][1] << 32);
                *(unsigned long long*)&pbuf[w][sub][qi][pc * 4 + (g & 1) * 2] = pack64;
            }
        }

        // ---- PV: acc[v][q] += V^T . P ----
        #pragma unroll
        for (int sub = 0; sub < 4; ++sub) {
            s16x8 pf = *(const s16x8*)&pbuf[w][sub][qi][pcr * 4];
            acc[sub][0] = __builtin_amdgcn_mfma_f32_16x16x32_bf16(vf0, pf, acc[sub][0], 0, 0, 0);
            acc[sub][1] = __builtin_amdgcn_mfma_f32_16x16x32_bf16(vf1, pf, acc[sub][1], 0, 0, 0);
        }
    }

    // ---- merge the 8 wave-partials ----
    #pragma unroll
    for (int sub = 0; sub < 4; ++sub) {
        float lv = l_run[sub];
        lv += __shfl_xor(lv, 16);
        lv += __shfl_xor(lv, 32);
        if (g == 0) lbuf[w][sub][qi] = lv;
    }
    __syncthreads();

    #pragma unroll
    for (int sub = 0; sub < 4; ++sub)
        #pragma unroll
        for (int vt = 0; vt < 2; ++vt)
            #pragma unroll
            for (int r = 0; r < 4; ++r)
                atomicAdd(&sumb[sub][vt * 16 + g * 4 + r][qi], acc[sub][vt][r]);
    __syncthreads();

    {
        const int sub = tid >> 7;
        const int q   = (tid >> 3) & 15;
        const int v0  = (tid & 7) * 4;
        float lt = 0.f;
        #pragma unroll
        for (int ww = 0; ww < NW; ++ww) lt += lbuf[ww][sub][q];
        const float inv = 1.0f / lt;
        float* op = OUT + ((size_t)(b * N + q0 + sub * 16 + q)) * D + v0;
        #pragma unroll
        for (int i = 0; i < 4; ++i) op[i] = sumb[sub][v0 + i][q] * inv;
    }
}

// ---------------- fallback (R1-style, passed in R1) if ws too small ----------------
__global__ __launch_bounds__(256, 2)
void mads_fb_kernel(const float* __restrict__ K,
                    const float* __restrict__ V,
                    const float* __restrict__ Q,
                    const float* __restrict__ Wp,
                    float* __restrict__ OUT)
{
    constexpr int N  = 4096, D = 32;
    constexpr int NW = 4;
    constexpr int KPW = N / NW;
    constexpr int RND = KPW / 32;

    __shared__ __align__(16) unsigned int pbuf[NW][4][16][16];
    __shared__ float mlbuf[NW][4][16][2];
    __shared__ float sumb[4][32][16];

    const int tid  = threadIdx.x;
    const int lane = tid & 63;
    const int w    = tid >> 6;
    const int g    = lane >> 4;
    const int qi   = lane & 15;
    const int b    = blockIdx.x >> 6;
    const int q0   = (blockIdx.x & 63) * 64;

    for (int i = tid; i < 4 * 32 * 16; i += 256) ((float*)sumb)[i] = 0.f;

    float w8[8];
    {
        const float* wp = Wp + g * 8;
        #pragma unroll
        for (int j = 0; j < 8; ++j) w8[j] = wp[j];
    }

    s16x8 qhi[4], qlo[4];
    #pragma unroll
    for (int sub = 0; sub < 4; ++sub) {
        const float* qp = Q + ((size_t)(b * N + q0 + sub * 16 + qi)) * D + g * 8;
        #pragma unroll
        for (int j = 0; j < 8; ++j) {
            float qs = qp[j] * w8[j];
            unsigned int h = f2bf(qs);
            qhi[sub][j] = (short)h;
            qlo[sub][j] = (short)f2bf(qs - bf2f(h));
        }
    }

    f32x4 acc[4][2];
    #pragma unroll
    for (int s = 0; s < 4; ++s)
        #pragma unroll
        for (int v = 0; v < 2; ++v)
            #pragma unroll
            for (int i = 0; i < 4; ++i) acc[s][v][i] = 0.f;

    float m_run[4] = {-1e30f, -1e30f, -1e30f, -1e30f};
    float l_run[4] = {0.f, 0.f, 0.f, 0.f};

    for (int rnd = 0; rnd < RND; ++rnd) {
        const int kb = w * KPW + rnd * 32;

        float kraw[2][8], vraw[2][8];
        #pragma unroll
        for (int kst = 0; kst < 2; ++kst) {
            const float* kp = K + ((size_t)(b * N + kb + kst * 16 + qi)) * D + g * 8;
            #pragma unroll
            for (int j = 0; j < 8; ++j) kraw[kst][j] = kp[j];
        }
        #pragma unroll
        for (int vt = 0; vt < 2; ++vt) {
            const float* vp = V + ((size_t)(b * N + kb + g * 8)) * D + vt * 16 + qi;
            #pragma unroll
            for (int j = 0; j < 8; ++j) vraw[vt][j] = vp[(size_t)j * D];
        }

        s16x8 khi[2], klo[2];
        f32x4 k2c[2];
        #pragma unroll
        for (int kst = 0; kst < 2; ++kst) {
            float pk = 0.f;
            #pragma unroll
            for (int j = 0; j < 8; ++j) {
                float ks = kraw[kst][j] * w8[j];
                pk = fmaf(ks, ks, pk);
                unsigned int h = f2bf(ks);
                khi[kst][j] = (short)h;
                klo[kst][j] = (short)f2bf(ks - bf2f(h));
            }
            pk += __shfl_xor(pk, 16);
            pk += __shfl_xor(pk, 32);
            pk *= -0.5f;
            #pragma unroll
            for (int r = 0; r < 4; ++r)
                k2c[kst][r] = __shfl(pk, ((lane >> 4) << 2) + r);
        }

        #pragma unroll
        for (int sub = 0; sub < 4; ++sub) {
            f32x4 sv[2];
            sv[0] = k2c[0];
            sv[1] = k2c[1];
            sv[0] = __builtin_amdgcn_mfma_f32_16x16x32_bf16(klo[0], qhi[sub], sv[0], 0, 0, 0);
            sv[0] = __builtin_amdgcn_mfma_f32_16x16x32_bf16(khi[0], qlo[sub], sv[0], 0, 0, 0);
            sv[0] = __builtin_amdgcn_mfma_f32_16x16x32_bf16(khi[0], qhi[sub], sv[0], 0, 0, 0);
            sv[1] = __builtin_amdgcn_mfma_f32_16x16x32_bf16(klo[1], qhi[sub], sv[1], 0, 0, 0);
            sv[1] = __builtin_amdgcn_mfma_f32_16x16x32_bf16(khi[1], qlo[sub], sv[1], 0, 0, 0);
            sv[1] = __builtin_amdgcn_mfma_f32_16x16x32_bf16(khi[1], qhi[sub], sv[1], 0, 0, 0);

            float tm = sv[0][0];
            tm = fmaxf(tm, sv[0][1]); tm = fmaxf(tm, sv[0][2]); tm = fmaxf(tm, sv[0][3]);
            tm = fmaxf(tm, sv[1][0]); tm = fmaxf(tm, sv[1][1]);
            tm = fmaxf(tm, sv[1][2]); tm = fmaxf(tm, sv[1][3]);
            tm = fmaxf(tm, __shfl_xor(tm, 16));
            tm = fmaxf(tm, __shfl_xor(tm, 32));

            float mnew  = fmaxf(m_run[sub], tm);
            float scale = exp2_hw((m_run[sub] - mnew) * L2E);
            m_run[sub]  = mnew;
            float nmL   = -mnew * L2E;

            acc[sub][0] *= scale;
            acc[sub][1] *= scale;

            float ps = 0.f;
            unsigned int pd[2][2];
            #pragma unroll
            for (int kst = 0; kst < 2; ++kst) {
                float p[4];
                #pragma unroll
                for (int r = 0; r < 4; ++r) {
                    p[r] = exp2_hw(fmaf(sv[kst][r], L2E, nmL));
                    ps += p[r];
                }
                pd[kst][0] = f2bf(p[0]) | (f2bf(p[1]) << 16);
                pd[kst][1] = f2bf(p[2]) | (f2bf(p[3]) << 16);
            }
            l_run[sub] = l_run[sub] * scale + ps;

            #pragma unroll
            for (int kst = 0; kst < 2; ++kst) {
                int c  = kst * 2 + (g >> 1);
                int pc = (c + (qi >> 1)) & 3;
                unsigned long long pack64 =
                    (unsigned long long)pd[kst][0] |
                    ((unsigned long long)pd[kst][1] << 32);
                *(unsigned long long*)&pbuf[w][sub][qi][pc * 4 + (g & 1) * 2] = pack64;
            }
        }

        s16x8 vfr[2];
        #pragma unroll
        for (int vt = 0; vt < 2; ++vt)
            #pragma unroll
            for (int j = 0; j < 8; ++j) vfr[vt][j] = (short)f2bf(vraw[vt][j]);

        const int pcr = (g + (qi >> 1)) & 3;
        #pragma unroll
        for (int sub = 0; sub < 4; ++sub) {
            s16x8 pf = *(const s16x8*)&pbuf[w][sub][qi][pcr * 4];
            acc[sub][0] = __builtin_amdgcn_mfma_f32_16x16x32_bf16(vfr[0], pf, acc[sub][0], 0, 0, 0);
            acc[sub][1] = __builtin_amdgcn_mfma_f32_16x16x32_bf16(vfr[1], pf, acc[sub][1], 0, 0, 0);
        }
    }

    #pragma unroll
    for (int sub = 0; sub < 4; ++sub) {
        float lv = l_run[sub];
        lv += __shfl_xor(lv, 16);
        lv += __shfl_xor(lv, 32);
        l_run[sub] = lv;
    }
    if (g == 0) {
        #pragma unroll
        for (int sub = 0; sub < 4; ++sub) {
            mlbuf[w][sub][qi][0] = m_run[sub];
            mlbuf[w][sub][qi][1] = l_run[sub];
        }
    }
    __syncthreads();

    #pragma unroll
    for (int sub = 0; sub < 4; ++sub) {
        float M = -1e30f;
        float mv[NW], lv[NW];
        #pragma unroll
        for (int ww = 0; ww < NW; ++ww) {
            mv[ww] = mlbuf[ww][sub][qi][0];
            lv[ww] = mlbuf[ww][sub][qi][1];
            M = fmaxf(M, mv[ww]);
        }
        float denom = 0.f;
        #pragma unroll
        for (int ww = 0; ww < NW; ++ww)
            denom += lv[ww] * exp2_hw((mv[ww] - M) * L2E);
        float sc = exp2_hw((m_run[sub] - M) * L2E) / denom;
        #pragma unroll
        for (int vt = 0; vt < 2; ++vt)
            #pragma unroll
            for (int r = 0; r < 4; ++r)
                atomicAdd(&sumb[sub][vt * 16 + g * 4 + r][qi], acc[sub][vt][r] * sc);
    }
    __syncthreads();

    {
        const int sub = tid >> 6;
        const int q   = (tid >> 2) & 15;
        const int v0  = (tid & 3) * 8;
        float* op = OUT + ((size_t)(b * N + q0 + sub * 16 + q)) * D + v0;
        #pragma unroll
        for (int i = 0; i < 8; ++i) op[i] = sumb[sub][v0 + i][q];
    }
}

extern "C" void kernel_launch(void* const* d_in, const int* in_sizes, int n_in,
                              void* d_out, int out_size, void* d_ws, size_t ws_size,
                              hipStream_t stream) {
    const float* K  = (const float*)d_in[0];
    const float* V  = (const float*)d_in[1];
    const float* Q  = (const float*)d_in[2];
    const float* W  = (const float*)d_in[3];
    float* OUT = (float*)d_out;
    (void)in_sizes; (void)n_in; (void)out_size;

    constexpr size_t PKS_EL = (size_t)8 * 128 * 6 * 512;   // 3.15M shorts
    constexpr size_t NROW   = (size_t)8 * 4096;
    constexpr size_t NEED   = PKS_EL * 2 + NROW * 4;       // ~6.42 MB

    if (ws_size >= NEED) {
        unsigned short* pks = (unsigned short*)d_ws;
        float*          k2s = (float*)(pks + PKS_EL);
        hipLaunchKernelGGL(prep_k2_kernel,   dim3(1024), dim3(256), 0, stream, K, W, k2s);
        hipLaunchKernelGGL(prep_pack_kernel, dim3(1536), dim3(256), 0, stream, K, V, W, pks);
        hipLaunchKernelGGL(mads_main_kernel, dim3(512),  dim3(512), 0, stream,
                           pks, k2s, Q, W, OUT);
    } else {
        hipLaunchKernelGGL(mads_fb_kernel, dim3(512), dim3(256), 0, stream,
                           K, V, Q, W, OUT);
    }
}